// Round 4
// baseline (908.605 us; speedup 1.0000x reference)
//
#include <hip/hip_runtime.h>

// GeneralizedInteractionNet on MI355X (gfx950). R13: kZero acc-init, DMA
// staging from pre-swizzled global, 4-wave blocks.
//
// Per layer:  M[n,D,d] = W[n,D,d]*h[n,d]
//   GEMM1: C[b,i,D] = sum_d Bi[b,i,d] * M[n,D,d]
//   GEMM2: R[b,i,D] = sum_f AT[n,i,f] * B0T[b,D,f]^T
//   out[b,n,D] = sum_i C[b,i,D]*R[b,i,D]
// i padded 40->64 (2 row tiles of 32); f padded 40->48 (3 K-steps of 16).
//
// History:
//  R9 (263us): L2-direct frags. MfmaUtil 39%. R10 (361us): failed reg-dbuf.
//  R11 (261us): 4-chain interleave = noise -> inter-chain latency refuted.
//  R12 (235us): LDS staging + XCD grouping; FETCH 46->13.7MB, MfmaUtil 47%.
//    Counters: MFMA 47% + VALU 27% + LDS 4% ~= wall -> pipes ADDITIVE.
//    VALU breakdown: 256 acc-zero v_movs per wave per n = half of VALU.
//  R13: (1) persistent zero f32x16 as C-input of each chain's first MFMA
//    (D!=C legal) -> zero-init VALU deleted. (2) global_load_lds DMA from
//    M pre-SWIZZLED in global / AT pre-padded (stride 56) in global; LDS
//    linear dest, swizzle applied on ds_read (m173 both-sides rule).
//    (3) 256-thr blocks (4 waves, 8 b), 1-n dbuf chunks (30KB LDS) -> 4
//    blocks/CU, smaller barrier convoys, backfill slack (grid 1024).

typedef __bf16 bf16x8 __attribute__((ext_vector_type(8)));
typedef float  f32x16 __attribute__((ext_vector_type(16)));
typedef unsigned short us4 __attribute__((ext_vector_type(4)));

constexpr int BATCH = 2048;
constexpr int FDIM  = 40;
constexpr int DDIM  = 64;
constexpr int LAY   = 3;
constexpr int FPAD  = 48;   // f padding for B0T (3 K-steps of 16)
constexpr int APAD  = 56;   // AT row stride in ushorts (112B -> 4-way max)
constexpr int NSPL  = 4;    // n-loop split across 4 blocks
constexpr int NPB   = FDIM / NSPL;    // 10 n per block
constexpr int BPB   = 8;    // b per block (4 waves x b2=2)
constexpr int MSLAB = DDIM * DDIM;    // 4096 ushort per n (8 KB)
constexpr int ASLAB = DDIM * APAD;    // 3584 ushort per n (7 KB)

__device__ __forceinline__ unsigned short f2bf(float f) {
  union { float f; unsigned u; } v; v.f = f;
  unsigned r = v.u + 0x7fff + ((v.u >> 16) & 1);   // round-to-nearest-even
  return (unsigned short)(r >> 16);
}

__device__ __forceinline__ void dma16(unsigned short* lds, const unsigned short* g) {
  __builtin_amdgcn_global_load_lds(
      (const __attribute__((address_space(1))) unsigned int*)g,
      (__attribute__((address_space(3))) unsigned int*)lds, 16, 0, 0);
}

// Single prep launch, role by blockIdx.x:
//  blocks [0, BATCH):  B0b[b,f,d] = bf16(inputs); B0T[b,d,f48] via LDS transpose
//  blocks [BATCH, ..): Mswz (pre-swizzled W*h), ATp (alpha^T, stride-56, zero-pad)
__global__ __launch_bounds__(256) void prep_all(
    const float* __restrict__ inputs, const float* __restrict__ W,
    const float* __restrict__ h, const float* __restrict__ alpha,
    unsigned short* __restrict__ B0b, unsigned short* __restrict__ B0T,
    unsigned short* __restrict__ M, unsigned short* __restrict__ AT) {
  __shared__ float lds[FDIM][DDIM + 1];
  if (blockIdx.x < BATCH) {
    const int b = blockIdx.x;
    const float* src = inputs + (size_t)b * FDIM * DDIM;
    for (int cch = threadIdx.x; cch < FDIM * DDIM / 4; cch += 256) {
      float4 v = reinterpret_cast<const float4*>(src)[cch];
      int e = cch * 4;
      int f = e >> 6, d = e & 63;
      lds[f][d] = v.x; lds[f][d + 1] = v.y; lds[f][d + 2] = v.z; lds[f][d + 3] = v.w;
      us4 o = { f2bf(v.x), f2bf(v.y), f2bf(v.z), f2bf(v.w) };
      reinterpret_cast<us4*>(B0b + (size_t)b * FDIM * DDIM)[cch] = o;
    }
    __syncthreads();
    for (int cch = threadIdx.x; cch < DDIM * FPAD / 4; cch += 256) {
      int f4 = cch % (FPAD / 4);
      int d  = cch / (FPAD / 4);
      us4 o = {0, 0, 0, 0};
      if (f4 < FDIM / 4) {
        int f = f4 * 4;
        o[0] = f2bf(lds[f][d]);     o[1] = f2bf(lds[f + 1][d]);
        o[2] = f2bf(lds[f + 2][d]); o[3] = f2bf(lds[f + 3][d]);
      }
      reinterpret_cast<us4*>(B0T + (size_t)b * DDIM * FPAD)[cch] = o;
    }
    return;
  }
  int j = (blockIdx.x - BATCH) * 256 + threadIdx.x;
  const int nM4 = LAY * FDIM * MSLAB / 4;    // 122880
  const int nA4 = LAY * FDIM * ASLAB / 4;    // 107520
  if (j < nM4) {
    // Mswz linear pos e = row*64 + jc*8 + o holds M[ln][row][(jc^(row&7))*8+o]
    // so the layer's swizzled ds_read (chunk ^= c&7) lands on natural data.
    int e   = j * 4;
    int ln  = e >> 12;
    int row = (e >> 6) & 63;
    int jc  = (e >> 3) & 7;
    int o   = e & 7;                      // 0 or 4
    int ds  = ((jc ^ (row & 7)) << 3) + o;
    float4 wv = *reinterpret_cast<const float4*>(W + ((size_t)ln * 64 + row) * 64 + ds);
    float4 hv = *reinterpret_cast<const float4*>(h + (size_t)ln * 64 + ds);
    us4 ov = { f2bf(wv.x * hv.x), f2bf(wv.y * hv.y), f2bf(wv.z * hv.z), f2bf(wv.w * hv.w) };
    *reinterpret_cast<us4*>(M + e) = ov;
    return;
  }
  j -= nM4;
  if (j >= nA4) return;
  {
    int e  = j * 4;
    int f  = e % APAD;
    int ii = (e / APAD) & 63;
    int n  = (e / ASLAB) % FDIM;
    int l  = e / (ASLAB * FDIM);
    us4 o = {0, 0, 0, 0};
    if (ii < FDIM) {
#pragma unroll
      for (int k = 0; k < 4; ++k)
        if (f + k < FDIM)
          o[k] = f2bf(alpha[(((size_t)l * FDIM + f + k) * FDIM + ii) * FDIM + n]);
    }
    *reinterpret_cast<us4*>(AT + e) = o;
  }
}

// mfma_f32_32x32x16_bf16 conventions:
//   A[m=lane&31][k=8*(lane>>5)+j]  B[k=8*(lane>>5)+j][col=lane&31]
//   C/D: col=lane&31, row=(reg&3)+8*(reg>>2)+4*(lane>>5)   [HW-verified]
template <bool FINAL>
__global__ __launch_bounds__(256, 4) void layer_k(
    const unsigned short* __restrict__ Bi,   // bf16 [B][40][64] (prev layer / B0b)
    const unsigned short* __restrict__ B0T,  // bf16 [B][64][48]
    const unsigned short* __restrict__ Mt,   // [40][4096] bf16 PRE-SWIZZLED
    const unsigned short* __restrict__ ATt,  // [40][64x56] bf16 zero-padded
    void* __restrict__ outp)                 // bf16 intermediate or f32 final
{
  // Double-buffered 1-n chunks, filled by global_load_lds DMA (linear dest).
  __shared__ unsigned short smM[2][MSLAB];
  __shared__ unsigned short smA[2][ASLAB];

  const int tid  = threadIdx.x;
  const int lane = tid & 63;
  const int w    = tid >> 6;                  // wave 0..3
  const int c    = lane & 31;
  const int h    = lane >> 5;

  // XCD grouping: physical d -> logical L = (d&7)*128 + d>>3; each XCD owns
  // 128 consecutive L = 32 b-groups x all 4 n-splits -> Bi/B0T of a b-group
  // lives in exactly one L2.
  const int L  = (blockIdx.x & 7) * 128 + (blockIdx.x >> 3);
  const int bg = L >> 2;                      // 0..255
  const int ns = L & 3;                       // n-quarter
  const int nBase = ns * NPB;
  const int bb = bg * BPB + w * 2;            // wave's first batch element

  // ---- wave-constant register fragments (loaded once, reused over 10 n) ----
  bf16x8 aBi[2][2][4];
#pragma unroll
  for (int b2 = 0; b2 < 2; ++b2)
#pragma unroll
    for (int it = 0; it < 2; ++it) {
      int row = it * 32 + c; if (row > FDIM - 1) row = FDIM - 1;
#pragma unroll
      for (int ks = 0; ks < 4; ++ks)
        aBi[b2][it][ks] = *reinterpret_cast<const bf16x8*>(
            Bi + ((size_t)(bb + b2) * FDIM + row) * DDIM + ks * 16 + h * 8);
    }
  bf16x8 bT[2][2][3];
#pragma unroll
  for (int b2 = 0; b2 < 2; ++b2)
#pragma unroll
    for (int dt = 0; dt < 2; ++dt)
#pragma unroll
      for (int ks = 0; ks < 3; ++ks)
        bT[b2][dt][ks] = *reinterpret_cast<const bf16x8*>(
            B0T + ((size_t)(bb + b2) * DDIM + dt * 32 + c) * FPAD + ks * 16 + h * 8);

  // Persistent zero C-input: first MFMA of every chain reads this (D != C),
  // eliminating 256 acc-zero v_movs per wave per n.
  const f32x16 z16 = {0,0,0,0,0,0,0,0,0,0,0,0,0,0,0,0};

  // ---- DMA one n-slab (M 512 + AT 448 x 16B chunks) into buffer bs ----
  auto dmaChunk = [&](int nl, int bs) {
    const unsigned short* Ms = Mt  + (size_t)(nBase + nl) * MSLAB;
    const unsigned short* As = ATt + (size_t)(nBase + nl) * ASLAB;
#pragma unroll
    for (int r = 0; r < 2; ++r) {
      int k = tid + r * 256;                 // 0..511
      dma16(&smM[bs][k * 8], Ms + k * 8);
    }
    dma16(&smA[bs][tid * 8], As + tid * 8);
    if (tid < 192) dma16(&smA[bs][(tid + 256) * 8], As + (tid + 256) * 8);
  };

  auto compute = [&](int nl, int bs) {
    const int n = nBase + nl;
    const unsigned short* mL = &smM[bs][0];
    const unsigned short* aL = &smA[bs][0];
    // 14 x ds_read_b128; M swizzle folded into prep -> read chunk ^= c&7.
    bf16x8 mb[2][4], at[2][3];
#pragma unroll
    for (int dt = 0; dt < 2; ++dt)
#pragma unroll
      for (int ks = 0; ks < 4; ++ks)
        mb[dt][ks] = *reinterpret_cast<const bf16x8*>(
            mL + (dt * 32 + c) * 64 + (((ks * 2 + h) ^ (c & 7)) * 8));
#pragma unroll
    for (int it = 0; it < 2; ++it)
#pragma unroll
      for (int ks = 0; ks < 3; ++ks)
        at[it][ks] = *reinterpret_cast<const bf16x8*>(
            aL + (it * 32 + c) * APAD + (ks * 2 + h) * 8);

    float pout[2][2] = {{0.f, 0.f}, {0.f, 0.f}};
#pragma unroll
    for (int it = 0; it < 2; ++it) {
#pragma unroll
      for (int dt = 0; dt < 2; ++dt) {
#pragma unroll
        for (int b2 = 0; b2 < 2; ++b2) {
          __builtin_amdgcn_s_setprio(1);
          f32x16 aC = __builtin_amdgcn_mfma_f32_32x32x16_bf16(aBi[b2][it][0], mb[dt][0], z16, 0, 0, 0);
          f32x16 aR = __builtin_amdgcn_mfma_f32_32x32x16_bf16(at[it][0], bT[b2][dt][0], z16, 0, 0, 0);
#pragma unroll
          for (int ks = 1; ks < 3; ++ks) {
            aC = __builtin_amdgcn_mfma_f32_32x32x16_bf16(aBi[b2][it][ks], mb[dt][ks], aC, 0, 0, 0);
            aR = __builtin_amdgcn_mfma_f32_32x32x16_bf16(at[it][ks], bT[b2][dt][ks], aR, 0, 0, 0);
          }
          aC = __builtin_amdgcn_mfma_f32_32x32x16_bf16(aBi[b2][it][3], mb[dt][3], aC, 0, 0, 0);
          __builtin_amdgcn_s_setprio(0);
          float t0 = 0.f, t1 = 0.f, t2 = 0.f, t3 = 0.f;
#pragma unroll
          for (int r = 0; r < 4; ++r) {
            t0 += aC[r] * aR[r];         t1 += aC[r + 4] * aR[r + 4];
            t2 += aC[r + 8] * aR[r + 8]; t3 += aC[r + 12] * aR[r + 12];
          }
          pout[b2][dt] += (t0 + t1) + (t2 + t3);
        }
      }
    }
#pragma unroll
    for (int b2 = 0; b2 < 2; ++b2) {
      float v0 = pout[b2][0] + __shfl_xor(pout[b2][0], 32, 64);
      float v1 = pout[b2][1] + __shfl_xor(pout[b2][1], 32, 64);
      float val = h ? v1 : v0;
      size_t off = ((size_t)(bb + b2) * FDIM + n) * DDIM + lane;
      if (FINAL) ((float*)outp)[off] = val;
      else       ((unsigned short*)outp)[off] = f2bf(val);
    }
  };

  // ---- main: dbuf 1-n chunks; DMA(n+1) issued before compute(n); barrier
  // (vmcnt(0)+lgkmcnt(0)) drains the DMA under the ~2700cy compute. ----
  dmaChunk(0, 0);
  __syncthreads();
#pragma unroll 1
  for (int cc = 0; cc < NPB; ++cc) {
    const int bs = cc & 1;
    if (cc + 1 < NPB) dmaChunk(cc + 1, bs ^ 1);
    compute(cc, bs);
    __syncthreads();
  }
}

extern "C" void kernel_launch(void* const* d_in, const int* in_sizes, int n_in,
                              void* d_out, int out_size, void* d_ws, size_t ws_size,
                              hipStream_t stream) {
  const float* inputs = (const float*)d_in[0];  // [2048,40,64]
  const float* W      = (const float*)d_in[1];  // [3,40,64,64]
  const float* alpha  = (const float*)d_in[2];  // [3,40,40,40]
  const float* h      = (const float*)d_in[3];  // [3,40,64,1]

  char* ws = (char*)d_ws;
  const size_t S   = (size_t)BATCH * FDIM * DDIM * 2;   // 10.49 MB bf16 buffer
  const size_t ST  = (size_t)BATCH * DDIM * FPAD * 2;   // 12.58 MB B0T
  unsigned short* Bi1 = (unsigned short*)(ws);
  unsigned short* Bi2 = (unsigned short*)(ws + S);
  unsigned short* B0b = (unsigned short*)(ws + 2 * S);
  unsigned short* B0T = (unsigned short*)(ws + 3 * S);
  unsigned short* Mb  = (unsigned short*)(ws + 3 * S + ST);
  unsigned short* ATb = (unsigned short*)(ws + 3 * S + ST + (size_t)LAY * FDIM * MSLAB * 2);

  const int nPrep4 = (LAY * FDIM * MSLAB + LAY * FDIM * ASLAB) / 4;   // 230400
  const int prepBlocks = BATCH + (nPrep4 + 255) / 256;                // 2048 + 900
  prep_all<<<prepBlocks, 256, 0, stream>>>(inputs, W, h, alpha, B0b, B0T, Mb, ATb);

  dim3 grid(BATCH / BPB * NSPL), blk(256);   // 1024 blocks, 4 waves, 8 b each
  const size_t mL = (size_t)FDIM * MSLAB;
  const size_t aL = (size_t)FDIM * ASLAB;
  layer_k<false><<<grid, blk, 0, stream>>>(B0b, B0T, Mb, ATb, Bi1);
  layer_k<false><<<grid, blk, 0, stream>>>(Bi1, B0T, Mb + mL, ATb + aL, Bi2);
  layer_k<true ><<<grid, blk, 0, stream>>>(Bi2, B0T, Mb + 2 * mL, ATb + 2 * aL, d_out);
}

// Round 5
// 240.186 us; speedup vs baseline: 3.7829x; 3.7829x over previous
//
#include <hip/hip_runtime.h>

// GeneralizedInteractionNet on MI355X (gfx950). R14: R13 structure at the
// CORRECT occupancy bound (256 regs, 2 waves/SIMD).
//
// Per layer:  M[n,D,d] = W[n,D,d]*h[n,d]
//   GEMM1: C[b,i,D] = sum_d Bi[b,i,d] * M[n,D,d]
//   GEMM2: R[b,i,D] = sum_f AT[n,i,f] * B0T[b,D,f]^T
//   out[b,n,D] = sum_i C[b,i,D]*R[b,i,D]
// i padded 40->64 (2 row tiles of 32); f padded 40->48 (3 K-steps of 16).
//
// History:
//  R9 (263us): L2-direct frags. MfmaUtil 39%. R10 (361us): failed reg-dbuf.
//  R11 (261us): 4-chain interleave = noise -> inter-chain latency refuted.
//  R12 (235us): LDS staging + XCD grouping; FETCH 46->13.7MB, MfmaUtil 47%.
//    MFMA 47% + VALU 27% + LDS 4% ~= wall -> pipes additive; half of VALU =
//    256 acc-zero v_movs per wave per n.
//  R13 (908us FAILED): right ideas, wrong launch_bounds(256,4): 4 waves/SIMD
//    caps unified VGPR+AGPR at 128 < ~236 needed -> ~170 regs spilled;
//    VGPR_Count=64, WRITE 331MB, FETCH 860MB = scratch traffic. (Same
//    mistake as R6/R8.) DMA+pre-swizzle path IS functionally verified.
//  R14: launch_bounds(256,2) -> 256-reg budget, no spill, 2 waves/SIMD
//    (same as R12). Keeps: (1) persistent-zero C-input kills all acc-zero
//    VALU, (2) global_load_lds DMA from pre-swizzled M / pre-padded AT
//    (linear LDS dest, swizzle on ds_read only -- m173 both-sides rule),
//    (3) 4-wave blocks, 1-n dbuf chunks, one barrier per n.

typedef __bf16 bf16x8 __attribute__((ext_vector_type(8)));
typedef float  f32x16 __attribute__((ext_vector_type(16)));
typedef unsigned short us4 __attribute__((ext_vector_type(4)));

constexpr int BATCH = 2048;
constexpr int FDIM  = 40;
constexpr int DDIM  = 64;
constexpr int LAY   = 3;
constexpr int FPAD  = 48;   // f padding for B0T (3 K-steps of 16)
constexpr int APAD  = 56;   // AT row stride in ushorts (112B -> 4-way max)
constexpr int NSPL  = 4;    // n-loop split across 4 blocks
constexpr int NPB   = FDIM / NSPL;    // 10 n per block
constexpr int BPB   = 8;    // b per block (4 waves x b2=2)
constexpr int MSLAB = DDIM * DDIM;    // 4096 ushort per n (8 KB)
constexpr int ASLAB = DDIM * APAD;    // 3584 ushort per n (7 KB)

__device__ __forceinline__ unsigned short f2bf(float f) {
  union { float f; unsigned u; } v; v.f = f;
  unsigned r = v.u + 0x7fff + ((v.u >> 16) & 1);   // round-to-nearest-even
  return (unsigned short)(r >> 16);
}

__device__ __forceinline__ void dma16(unsigned short* lds, const unsigned short* g) {
  __builtin_amdgcn_global_load_lds(
      (const __attribute__((address_space(1))) unsigned int*)g,
      (__attribute__((address_space(3))) unsigned int*)lds, 16, 0, 0);
}

// Single prep launch, role by blockIdx.x:
//  blocks [0, BATCH):  B0b[b,f,d] = bf16(inputs); B0T[b,d,f48] via LDS transpose
//  blocks [BATCH, ..): Mswz (pre-swizzled W*h), ATp (alpha^T, stride-56, zero-pad)
__global__ __launch_bounds__(256) void prep_all(
    const float* __restrict__ inputs, const float* __restrict__ W,
    const float* __restrict__ h, const float* __restrict__ alpha,
    unsigned short* __restrict__ B0b, unsigned short* __restrict__ B0T,
    unsigned short* __restrict__ M, unsigned short* __restrict__ AT) {
  __shared__ float lds[FDIM][DDIM + 1];
  if (blockIdx.x < BATCH) {
    const int b = blockIdx.x;
    const float* src = inputs + (size_t)b * FDIM * DDIM;
    for (int cch = threadIdx.x; cch < FDIM * DDIM / 4; cch += 256) {
      float4 v = reinterpret_cast<const float4*>(src)[cch];
      int e = cch * 4;
      int f = e >> 6, d = e & 63;
      lds[f][d] = v.x; lds[f][d + 1] = v.y; lds[f][d + 2] = v.z; lds[f][d + 3] = v.w;
      us4 o = { f2bf(v.x), f2bf(v.y), f2bf(v.z), f2bf(v.w) };
      reinterpret_cast<us4*>(B0b + (size_t)b * FDIM * DDIM)[cch] = o;
    }
    __syncthreads();
    for (int cch = threadIdx.x; cch < DDIM * FPAD / 4; cch += 256) {
      int f4 = cch % (FPAD / 4);
      int d  = cch / (FPAD / 4);
      us4 o = {0, 0, 0, 0};
      if (f4 < FDIM / 4) {
        int f = f4 * 4;
        o[0] = f2bf(lds[f][d]);     o[1] = f2bf(lds[f + 1][d]);
        o[2] = f2bf(lds[f + 2][d]); o[3] = f2bf(lds[f + 3][d]);
      }
      reinterpret_cast<us4*>(B0T + (size_t)b * DDIM * FPAD)[cch] = o;
    }
    return;
  }
  int j = (blockIdx.x - BATCH) * 256 + threadIdx.x;
  const int nM4 = LAY * FDIM * MSLAB / 4;    // 122880
  const int nA4 = LAY * FDIM * ASLAB / 4;    // 107520
  if (j < nM4) {
    // Mswz linear pos e = row*64 + jc*8 + o holds M[ln][row][(jc^(row&7))*8+o]
    // so the layer's swizzled ds_read (chunk ^= c&7) lands on natural data.
    int e   = j * 4;
    int ln  = e >> 12;
    int row = (e >> 6) & 63;
    int jc  = (e >> 3) & 7;
    int o   = e & 7;                      // 0 or 4
    int ds  = ((jc ^ (row & 7)) << 3) + o;
    float4 wv = *reinterpret_cast<const float4*>(W + ((size_t)ln * 64 + row) * 64 + ds);
    float4 hv = *reinterpret_cast<const float4*>(h + (size_t)ln * 64 + ds);
    us4 ov = { f2bf(wv.x * hv.x), f2bf(wv.y * hv.y), f2bf(wv.z * hv.z), f2bf(wv.w * hv.w) };
    *reinterpret_cast<us4*>(M + e) = ov;
    return;
  }
  j -= nM4;
  if (j >= nA4) return;
  {
    int e  = j * 4;
    int f  = e % APAD;
    int ii = (e / APAD) & 63;
    int n  = (e / ASLAB) % FDIM;
    int l  = e / (ASLAB * FDIM);
    us4 o = {0, 0, 0, 0};
    if (ii < FDIM) {
#pragma unroll
      for (int k = 0; k < 4; ++k)
        if (f + k < FDIM)
          o[k] = f2bf(alpha[(((size_t)l * FDIM + f + k) * FDIM + ii) * FDIM + n]);
    }
    *reinterpret_cast<us4*>(AT + e) = o;
  }
}

// mfma_f32_32x32x16_bf16 conventions:
//   A[m=lane&31][k=8*(lane>>5)+j]  B[k=8*(lane>>5)+j][col=lane&31]
//   C/D: col=lane&31, row=(reg&3)+8*(reg>>2)+4*(lane>>5)   [HW-verified]
template <bool FINAL>
__global__ __launch_bounds__(256, 2) void layer_k(
    const unsigned short* __restrict__ Bi,   // bf16 [B][40][64] (prev layer / B0b)
    const unsigned short* __restrict__ B0T,  // bf16 [B][64][48]
    const unsigned short* __restrict__ Mt,   // [40][4096] bf16 PRE-SWIZZLED
    const unsigned short* __restrict__ ATt,  // [40][64x56] bf16 zero-padded
    void* __restrict__ outp)                 // bf16 intermediate or f32 final
{
  // Double-buffered 1-n chunks, filled by global_load_lds DMA (linear dest).
  __shared__ unsigned short smM[2][MSLAB];
  __shared__ unsigned short smA[2][ASLAB];

  const int tid  = threadIdx.x;
  const int lane = tid & 63;
  const int w    = tid >> 6;                  // wave 0..3
  const int c    = lane & 31;
  const int h    = lane >> 5;

  // XCD grouping: physical d -> logical L = (d&7)*128 + d>>3; each XCD owns
  // 128 consecutive L = 32 b-groups x all 4 n-splits -> Bi/B0T of a b-group
  // lives in exactly one L2.
  const int L  = (blockIdx.x & 7) * 128 + (blockIdx.x >> 3);
  const int bg = L >> 2;                      // 0..255
  const int ns = L & 3;                       // n-quarter
  const int nBase = ns * NPB;
  const int bb = bg * BPB + w * 2;            // wave's first batch element

  // ---- wave-constant register fragments (loaded once, reused over 10 n) ----
  bf16x8 aBi[2][2][4];
#pragma unroll
  for (int b2 = 0; b2 < 2; ++b2)
#pragma unroll
    for (int it = 0; it < 2; ++it) {
      int row = it * 32 + c; if (row > FDIM - 1) row = FDIM - 1;
#pragma unroll
      for (int ks = 0; ks < 4; ++ks)
        aBi[b2][it][ks] = *reinterpret_cast<const bf16x8*>(
            Bi + ((size_t)(bb + b2) * FDIM + row) * DDIM + ks * 16 + h * 8);
    }
  bf16x8 bT[2][2][3];
#pragma unroll
  for (int b2 = 0; b2 < 2; ++b2)
#pragma unroll
    for (int dt = 0; dt < 2; ++dt)
#pragma unroll
      for (int ks = 0; ks < 3; ++ks)
        bT[b2][dt][ks] = *reinterpret_cast<const bf16x8*>(
            B0T + ((size_t)(bb + b2) * DDIM + dt * 32 + c) * FPAD + ks * 16 + h * 8);

  // Persistent zero C-input: first MFMA of every chain reads this (D != C),
  // eliminating 256 acc-zero v_movs per wave per n.
  const f32x16 z16 = {0,0,0,0,0,0,0,0,0,0,0,0,0,0,0,0};

  // ---- DMA one n-slab (M 512 + AT 448 x 16B chunks) into buffer bs ----
  auto dmaChunk = [&](int nl, int bs) {
    const unsigned short* Ms = Mt  + (size_t)(nBase + nl) * MSLAB;
    const unsigned short* As = ATt + (size_t)(nBase + nl) * ASLAB;
#pragma unroll
    for (int r = 0; r < 2; ++r) {
      int k = tid + r * 256;                 // 0..511
      dma16(&smM[bs][k * 8], Ms + k * 8);
    }
    dma16(&smA[bs][tid * 8], As + tid * 8);
    if (tid < 192) dma16(&smA[bs][(tid + 256) * 8], As + (tid + 256) * 8);
  };

  auto compute = [&](int nl, int bs) {
    const int n = nBase + nl;
    const unsigned short* mL = &smM[bs][0];
    const unsigned short* aL = &smA[bs][0];
    // 14 x ds_read_b128; M swizzle folded into prep -> read chunk ^= c&7.
    bf16x8 mb[2][4], at[2][3];
#pragma unroll
    for (int dt = 0; dt < 2; ++dt)
#pragma unroll
      for (int ks = 0; ks < 4; ++ks)
        mb[dt][ks] = *reinterpret_cast<const bf16x8*>(
            mL + (dt * 32 + c) * 64 + (((ks * 2 + h) ^ (c & 7)) * 8));
#pragma unroll
    for (int it = 0; it < 2; ++it)
#pragma unroll
      for (int ks = 0; ks < 3; ++ks)
        at[it][ks] = *reinterpret_cast<const bf16x8*>(
            aL + (it * 32 + c) * APAD + (ks * 2 + h) * 8);

    float pout[2][2] = {{0.f, 0.f}, {0.f, 0.f}};
#pragma unroll
    for (int it = 0; it < 2; ++it) {
#pragma unroll
      for (int dt = 0; dt < 2; ++dt) {
#pragma unroll
        for (int b2 = 0; b2 < 2; ++b2) {
          __builtin_amdgcn_s_setprio(1);
          f32x16 aC = __builtin_amdgcn_mfma_f32_32x32x16_bf16(aBi[b2][it][0], mb[dt][0], z16, 0, 0, 0);
          f32x16 aR = __builtin_amdgcn_mfma_f32_32x32x16_bf16(at[it][0], bT[b2][dt][0], z16, 0, 0, 0);
#pragma unroll
          for (int ks = 1; ks < 3; ++ks) {
            aC = __builtin_amdgcn_mfma_f32_32x32x16_bf16(aBi[b2][it][ks], mb[dt][ks], aC, 0, 0, 0);
            aR = __builtin_amdgcn_mfma_f32_32x32x16_bf16(at[it][ks], bT[b2][dt][ks], aR, 0, 0, 0);
          }
          aC = __builtin_amdgcn_mfma_f32_32x32x16_bf16(aBi[b2][it][3], mb[dt][3], aC, 0, 0, 0);
          __builtin_amdgcn_s_setprio(0);
          float t0 = 0.f, t1 = 0.f, t2 = 0.f, t3 = 0.f;
#pragma unroll
          for (int r = 0; r < 4; ++r) {
            t0 += aC[r] * aR[r];         t1 += aC[r + 4] * aR[r + 4];
            t2 += aC[r + 8] * aR[r + 8]; t3 += aC[r + 12] * aR[r + 12];
          }
          pout[b2][dt] += (t0 + t1) + (t2 + t3);
        }
      }
    }
#pragma unroll
    for (int b2 = 0; b2 < 2; ++b2) {
      float v0 = pout[b2][0] + __shfl_xor(pout[b2][0], 32, 64);
      float v1 = pout[b2][1] + __shfl_xor(pout[b2][1], 32, 64);
      float val = h ? v1 : v0;
      size_t off = ((size_t)(bb + b2) * FDIM + n) * DDIM + lane;
      if (FINAL) ((float*)outp)[off] = val;
      else       ((unsigned short*)outp)[off] = f2bf(val);
    }
  };

  // ---- main: dbuf 1-n chunks; DMA(n+1) issued before compute(n); barrier
  // (vmcnt(0)+lgkmcnt(0)) drains the DMA under the ~2700cy compute. ----
  dmaChunk(0, 0);
  __syncthreads();
#pragma unroll 1
  for (int cc = 0; cc < NPB; ++cc) {
    const int bs = cc & 1;
    if (cc + 1 < NPB) dmaChunk(cc + 1, bs ^ 1);
    compute(cc, bs);
    __syncthreads();
  }
}

extern "C" void kernel_launch(void* const* d_in, const int* in_sizes, int n_in,
                              void* d_out, int out_size, void* d_ws, size_t ws_size,
                              hipStream_t stream) {
  const float* inputs = (const float*)d_in[0];  // [2048,40,64]
  const float* W      = (const float*)d_in[1];  // [3,40,64,64]
  const float* alpha  = (const float*)d_in[2];  // [3,40,40,40]
  const float* h      = (const float*)d_in[3];  // [3,40,64,1]

  char* ws = (char*)d_ws;
  const size_t S   = (size_t)BATCH * FDIM * DDIM * 2;   // 10.49 MB bf16 buffer
  const size_t ST  = (size_t)BATCH * DDIM * FPAD * 2;   // 12.58 MB B0T
  unsigned short* Bi1 = (unsigned short*)(ws);
  unsigned short* Bi2 = (unsigned short*)(ws + S);
  unsigned short* B0b = (unsigned short*)(ws + 2 * S);
  unsigned short* B0T = (unsigned short*)(ws + 3 * S);
  unsigned short* Mb  = (unsigned short*)(ws + 3 * S + ST);
  unsigned short* ATb = (unsigned short*)(ws + 3 * S + ST + (size_t)LAY * FDIM * MSLAB * 2);

  const int nPrep4 = (LAY * FDIM * MSLAB + LAY * FDIM * ASLAB) / 4;   // 230400
  const int prepBlocks = BATCH + (nPrep4 + 255) / 256;                // 2048 + 900
  prep_all<<<prepBlocks, 256, 0, stream>>>(inputs, W, h, alpha, B0b, B0T, Mb, ATb);

  dim3 grid(BATCH / BPB * NSPL), blk(256);   // 1024 blocks, 4 waves, 8 b each
  const size_t mL = (size_t)FDIM * MSLAB;
  const size_t aL = (size_t)FDIM * ASLAB;
  layer_k<false><<<grid, blk, 0, stream>>>(B0b, B0T, Mb, ATb, Bi1);
  layer_k<false><<<grid, blk, 0, stream>>>(Bi1, B0T, Mb + mL, ATb + aL, Bi2);
  layer_k<true ><<<grid, blk, 0, stream>>>(Bi2, B0T, Mb + 2 * mL, ATb + 2 * aL, d_out);
}